// Round 1
// baseline (63.048 us; speedup 1.0000x reference)
//
#include <hip/hip_runtime.h>
#include <math.h>

// SpectralCompactnessLoss: B=2, C=32, K=2, N=H*W*D voxels
// ws layout (floats):
//   sums  : MIRRORS * (B*K*C=128)   feature sums per (b,k,c)
//   counts: MIRRORS * (B*K=4)       pixel counts per (b,k)
//   loss  : MIRRORS * (B*K=4)       weighted-distance sums per (b,k)

#define CCH 32
#define KCLS 2
#define BB 2
#define MIRRORS 16
#define SUMS_F (MIRRORS * BB * KCLS * CCH)   // 2048
#define CNTS_F (MIRRORS * BB * KCLS)         // 64
#define LOSS_F (MIRRORS * BB * KCLS)         // 64
#define WS_FLOATS (SUMS_F + CNTS_F + LOSS_F) // 2176

__device__ __forceinline__ float waveReduceSum(float v) {
#pragma unroll
    for (int o = 32; o > 0; o >>= 1) v += __shfl_down(v, o);
    return v;
}

// Pass 1: per-(b,k,c) feature sums and per-(b,k) counts.
// Blocks [0, halfG) handle b=0, [halfG, 2*halfG) handle b=1 (b uniform per block).
__global__ void __launch_bounds__(256) scl_pass1(
    const float* __restrict__ feat, const int* __restrict__ tgt,
    float* __restrict__ sums, float* __restrict__ counts,
    int N, int qPerB, int halfG) {
    const int b  = (blockIdx.x >= halfG) ? 1 : 0;
    const int lb = blockIdx.x - b * halfG;
    const int mir = blockIdx.x & (MIRRORS - 1);

    float acc0[CCH], acc1[CCH];
#pragma unroll
    for (int c = 0; c < CCH; ++c) { acc0[c] = 0.f; acc1[c] = 0.f; }
    float cnt0 = 0.f, cnt1 = 0.f;

    const float* fb = feat + (size_t)b * CCH * N;
    const int*   tb = tgt  + (size_t)b * N;

    for (int q = lb * blockDim.x + threadIdx.x; q < qPerB; q += halfG * blockDim.x) {
        const int n = q * 4;
        const int4 t4 = *reinterpret_cast<const int4*>(tb + n);
        const float m0x = (t4.x == 0) ? 1.f : 0.f, m1x = 1.f - m0x;
        const float m0y = (t4.y == 0) ? 1.f : 0.f, m1y = 1.f - m0y;
        const float m0z = (t4.z == 0) ? 1.f : 0.f, m1z = 1.f - m0z;
        const float m0w = (t4.w == 0) ? 1.f : 0.f, m1w = 1.f - m0w;
        cnt0 += m0x + m0y + m0z + m0w;
        cnt1 += m1x + m1y + m1z + m1w;
#pragma unroll
        for (int c = 0; c < CCH; ++c) {
            const float4 v = *reinterpret_cast<const float4*>(fb + (size_t)c * N + n);
            acc0[c] += v.x * m0x + v.y * m0y + v.z * m0z + v.w * m0w;
            acc1[c] += v.x * m1x + v.y * m1y + v.z * m1z + v.w * m1w;
        }
    }

    __shared__ float part[4][66];
    const int lane = threadIdx.x & 63;
    const int wv   = threadIdx.x >> 6;
#pragma unroll
    for (int c = 0; c < CCH; ++c) {
        float v = waveReduceSum(acc0[c]);
        if (lane == 0) part[wv][c] = v;
        v = waveReduceSum(acc1[c]);
        if (lane == 0) part[wv][CCH + c] = v;
    }
    {
        float v = waveReduceSum(cnt0);
        if (lane == 0) part[wv][64] = v;
        v = waveReduceSum(cnt1);
        if (lane == 0) part[wv][65] = v;
    }
    __syncthreads();
    const int t = threadIdx.x;
    if (t < 66) {
        const float s = part[0][t] + part[1][t] + part[2][t] + part[3][t];
        if (t < CCH) {
            atomicAdd(&sums[mir * (BB * KCLS * CCH) + (b * KCLS + 0) * CCH + t], s);
        } else if (t < 2 * CCH) {
            atomicAdd(&sums[mir * (BB * KCLS * CCH) + (b * KCLS + 1) * CCH + (t - CCH)], s);
        } else {
            atomicAdd(&counts[mir * (BB * KCLS) + b * KCLS + (t - 2 * CCH)], s);
        }
    }
}

// Pass 2: per-voxel weighted distance, accumulated per (b,k).
__global__ void __launch_bounds__(256) scl_pass2(
    const float* __restrict__ feat, const float* __restrict__ pred,
    const int* __restrict__ tgt,
    const float* __restrict__ sums, const float* __restrict__ counts,
    float* __restrict__ loss,
    int N, int qPerB, int halfG) {
    const int b  = (blockIdx.x >= halfG) ? 1 : 0;
    const int lb = blockIdx.x - b * halfG;
    const int mir = blockIdx.x & (MIRRORS - 1);

    __shared__ float ctr[KCLS * CCH];  // centers for this b: [k][c]
    if (threadIdx.x < KCLS * CCH) {
        const int k = threadIdx.x / CCH;
        const int c = threadIdx.x % CCH;
        float s = 0.f, cn = 0.f;
#pragma unroll
        for (int m = 0; m < MIRRORS; ++m) {
            s  += sums[m * (BB * KCLS * CCH) + (b * KCLS + k) * CCH + c];
            cn += counts[m * (BB * KCLS) + b * KCLS + k];
        }
        ctr[threadIdx.x] = s / fmaxf(cn, 1.f);
    }
    __syncthreads();

    const float* fb = feat + (size_t)b * CCH * N;
    const float* p0 = pred + (size_t)b * KCLS * N;
    const float* p1 = p0 + N;
    const int*   tb = tgt + (size_t)b * N;

    float accw0 = 0.f, accw1 = 0.f;

    for (int q = lb * blockDim.x + threadIdx.x; q < qPerB; q += halfG * blockDim.x) {
        const int n = q * 4;
        const int4   t4 = *reinterpret_cast<const int4*>(tb + n);
        const float4 a0 = *reinterpret_cast<const float4*>(p0 + n);
        const float4 a1 = *reinterpret_cast<const float4*>(p1 + n);

        float d2x = 0.f, d2y = 0.f, d2z = 0.f, d2w = 0.f;
#pragma unroll
        for (int c = 0; c < CCH; ++c) {
            const float4 v = *reinterpret_cast<const float4*>(fb + (size_t)c * N + n);
            const float c0 = ctr[c];
            const float c1 = ctr[CCH + c];
            float d;
            d = v.x - (t4.x ? c1 : c0); d2x += d * d;
            d = v.y - (t4.y ? c1 : c0); d2y += d * d;
            d = v.z - (t4.z ? c1 : c0); d2z += d * d;
            d = v.w - (t4.w ? c1 : c0); d2w += d * d;
        }
        // stable 2-class softmax confidence of own class
        float mx, e0, e1, cf, w;
        mx = fmaxf(a0.x, a1.x); e0 = __expf(a0.x - mx); e1 = __expf(a1.x - mx);
        cf = (t4.x ? e1 : e0) / (e0 + e1);
        w = sqrtf(d2x) * cf; accw0 += t4.x ? 0.f : w; accw1 += t4.x ? w : 0.f;

        mx = fmaxf(a0.y, a1.y); e0 = __expf(a0.y - mx); e1 = __expf(a1.y - mx);
        cf = (t4.y ? e1 : e0) / (e0 + e1);
        w = sqrtf(d2y) * cf; accw0 += t4.y ? 0.f : w; accw1 += t4.y ? w : 0.f;

        mx = fmaxf(a0.z, a1.z); e0 = __expf(a0.z - mx); e1 = __expf(a1.z - mx);
        cf = (t4.z ? e1 : e0) / (e0 + e1);
        w = sqrtf(d2z) * cf; accw0 += t4.z ? 0.f : w; accw1 += t4.z ? w : 0.f;

        mx = fmaxf(a0.w, a1.w); e0 = __expf(a0.w - mx); e1 = __expf(a1.w - mx);
        cf = (t4.w ? e1 : e0) / (e0 + e1);
        w = sqrtf(d2w) * cf; accw0 += t4.w ? 0.f : w; accw1 += t4.w ? w : 0.f;
    }

    __shared__ float part[4][2];
    const int lane = threadIdx.x & 63;
    const int wv   = threadIdx.x >> 6;
    float r0 = waveReduceSum(accw0);
    float r1 = waveReduceSum(accw1);
    if (lane == 0) { part[wv][0] = r0; part[wv][1] = r1; }
    __syncthreads();
    if (threadIdx.x < 2) {
        const float s = part[0][threadIdx.x] + part[1][threadIdx.x] +
                        part[2][threadIdx.x] + part[3][threadIdx.x];
        atomicAdd(&loss[mir * (BB * KCLS) + b * KCLS + threadIdx.x], s);
    }
}

// Pass 3: scalar epilogue.
__global__ void scl_pass3(const float* __restrict__ counts,
                          const float* __restrict__ loss,
                          float* __restrict__ out) {
    if (threadIdx.x == 0 && blockIdx.x == 0) {
        float total = 0.f, nv = 0.f;
#pragma unroll
        for (int bk = 0; bk < BB * KCLS; ++bk) {
            float cn = 0.f, ls = 0.f;
#pragma unroll
            for (int m = 0; m < MIRRORS; ++m) {
                cn += counts[m * (BB * KCLS) + bk];
                ls += loss[m * (BB * KCLS) + bk];
            }
            const float cl = ls / fmaxf(cn, 1.f);
            if (cn >= 2.f) { total += cl; nv += 1.f; }
        }
        out[0] = (nv > 0.f) ? (total / nv) : 0.f;
    }
}

extern "C" void kernel_launch(void* const* d_in, const int* in_sizes, int n_in,
                              void* d_out, int out_size, void* d_ws, size_t ws_size,
                              hipStream_t stream) {
    const float* feat = (const float*)d_in[0];
    const float* pred = (const float*)d_in[1];
    const int*   tgt  = (const int*)d_in[2];
    float* out = (float*)d_out;

    const int totalVox = in_sizes[2];     // B*N
    const int N = totalVox / BB;          // H*W*D
    const int qPerB = N / 4;              // float4 quads per batch

    float* sums   = (float*)d_ws;
    float* counts = sums + SUMS_F;
    float* loss   = counts + CNTS_F;

    hipMemsetAsync(d_ws, 0, WS_FLOATS * sizeof(float), stream);

    const int halfG = 384;                // 98304 threads per b: 1 quad/thread exactly
    dim3 grid(2 * halfG), block(256);
    scl_pass1<<<grid, block, 0, stream>>>(feat, tgt, sums, counts, N, qPerB, halfG);
    scl_pass2<<<grid, block, 0, stream>>>(feat, pred, tgt, sums, counts, loss, N, qPerB, halfG);
    scl_pass3<<<1, 64, 0, stream>>>(counts, loss, out);
}

// Round 2
// 47.961 us; speedup vs baseline: 1.3146x; 1.3146x over previous
//
#include <hip/hip_runtime.h>
#include <math.h>

// SpectralCompactnessLoss: B=2, C=32, K=2, N=H*W*D=393216 voxels per batch.
// 4 kernels, no atomics, no memset:
//   pass1 : channel-split masked sums   -> part[2048*2], cntPart[64]
//   reduce: centers[128], counts[4]
//   pass2 : per-voxel weighted distance -> lossPart[1536*2]
//   pass3 : final scalar
#define CCH 32
#define KCLS 2
#define BB 2
#define SSEG 32
#define P1_BLOCKS (BB * SSEG * CCH)        // 2048
#define P2_PER_B 768
#define P2_BLOCKS (BB * P2_PER_B)          // 1536

// ws float offsets
#define OFF_PART 0                          // P1_BLOCKS*2 = 4096
#define OFF_CNTP (OFF_PART + P1_BLOCKS * 2) // 64
#define OFF_CTR  (OFF_CNTP + BB * SSEG)     // 128
#define OFF_CNT  (OFF_CTR + BB * KCLS * CCH)// 4
#define OFF_LOSS (OFF_CNT + BB * KCLS)      // P2_BLOCKS*2

__device__ __forceinline__ float waveReduceSum(float v) {
#pragma unroll
    for (int o = 32; o > 0; o >>= 1) v += __shfl_down(v, o);
    return v;
}

// Pass 1: block = (b, s, c); streams one channel-row segment.
__global__ void __launch_bounds__(256) scl_pass1(
    const float* __restrict__ feat, const int* __restrict__ tgt,
    float* __restrict__ part, float* __restrict__ cntPart, int N) {
    const int blk = blockIdx.x;
    const int c = blk & (CCH - 1);
    const int s = (blk >> 5) & (SSEG - 1);
    const int b = blk >> 10;
    const int segVox = N / SSEG;           // 12288
    const int segQ = segVox / 4;           // 3072 -> 12 iters/thread

    const float* fb = feat + ((size_t)(b * CCH + c)) * N + (size_t)s * segVox;
    const int*   tb = tgt + (size_t)b * N + (size_t)s * segVox;

    float s1 = 0.f, st = 0.f, c1 = 0.f;
    for (int q = threadIdx.x; q < segQ; q += 256) {
        const int n = q * 4;
        const int4   t4 = *reinterpret_cast<const int4*>(tb + n);
        const float4 v  = *reinterpret_cast<const float4*>(fb + n);
        const float m1x = t4.x ? 1.f : 0.f;
        const float m1y = t4.y ? 1.f : 0.f;
        const float m1z = t4.z ? 1.f : 0.f;
        const float m1w = t4.w ? 1.f : 0.f;
        st += (v.x + v.y) + (v.z + v.w);
        s1 += v.x * m1x + v.y * m1y + v.z * m1z + v.w * m1w;
        c1 += (m1x + m1y) + (m1z + m1w);
    }

    __shared__ float sm[4][3];
    const int lane = threadIdx.x & 63;
    const int wv   = threadIdx.x >> 6;
    float r1 = waveReduceSum(s1);
    float rt = waveReduceSum(st);
    float rc = waveReduceSum(c1);
    if (lane == 0) { sm[wv][0] = r1; sm[wv][1] = rt; sm[wv][2] = rc; }
    __syncthreads();
    if (threadIdx.x == 0) {
        const float a1 = sm[0][0] + sm[1][0] + sm[2][0] + sm[3][0];
        const float at = sm[0][1] + sm[1][1] + sm[2][1] + sm[3][1];
        part[blk * 2 + 0] = a1;
        part[blk * 2 + 1] = at;
        if (c == 0) {
            const float ac = sm[0][2] + sm[1][2] + sm[2][2] + sm[3][2];
            cntPart[b * SSEG + s] = ac;
        }
    }
}

// Reduce: centers[b][k][c], counts[b][k]. One block, 64 threads.
__global__ void scl_reduce(const float* __restrict__ part,
                           const float* __restrict__ cntPart,
                           float* __restrict__ centers,
                           float* __restrict__ counts, int N) {
    __shared__ float cs[BB * 2];
    const int t = threadIdx.x;
    if (t < BB) {
        float c1 = 0.f;
#pragma unroll
        for (int s = 0; s < SSEG; ++s) c1 += cntPart[t * SSEG + s];
        const float c0 = (float)N - c1;
        cs[t * 2 + 0] = c0; cs[t * 2 + 1] = c1;
        counts[t * 2 + 0] = c0; counts[t * 2 + 1] = c1;
    }
    __syncthreads();
    if (t < BB * CCH) {
        const int b = t >> 5, c = t & 31;
        float s1 = 0.f, stt = 0.f;
#pragma unroll
        for (int s = 0; s < SSEG; ++s) {
            const float* p = part + ((size_t)((b * SSEG + s) * CCH + c)) * 2;
            s1  += p[0];
            stt += p[1];
        }
        const float c0 = cs[b * 2 + 0], c1v = cs[b * 2 + 1];
        centers[(b * KCLS + 0) * CCH + c] = (stt - s1) / fmaxf(c0, 1.f);
        centers[(b * KCLS + 1) * CCH + c] = s1 / fmaxf(c1v, 1.f);
    }
}

// Pass 2: float2 per thread; 768 blocks per batch.
__global__ void __launch_bounds__(256) scl_pass2(
    const float* __restrict__ feat, const float* __restrict__ pred,
    const int* __restrict__ tgt, const float* __restrict__ centers,
    float* __restrict__ lossPart, int N) {
    const int blk = blockIdx.x;
    const int b  = (blk >= P2_PER_B) ? 1 : 0;
    const int lb = blk - b * P2_PER_B;

    __shared__ float ctr[KCLS * CCH];
    if (threadIdx.x < KCLS * CCH)
        ctr[threadIdx.x] = centers[b * KCLS * CCH + threadIdx.x];
    __syncthreads();

    const int n = (lb * 256 + threadIdx.x) * 2;
    const float* fb = feat + (size_t)b * CCH * N;
    const float* p0 = pred + (size_t)b * KCLS * N;
    const float* p1 = p0 + N;
    const int*   tb = tgt + (size_t)b * N;

    const int2   t2 = *reinterpret_cast<const int2*>(tb + n);
    const float2 a0 = *reinterpret_cast<const float2*>(p0 + n);
    const float2 a1 = *reinterpret_cast<const float2*>(p1 + n);

    float d2x = 0.f, d2y = 0.f;
#pragma unroll
    for (int c = 0; c < CCH; ++c) {
        const float2 v = *reinterpret_cast<const float2*>(fb + (size_t)c * N + n);
        const float c0 = ctr[c], c1 = ctr[CCH + c];
        float d;
        d = v.x - (t2.x ? c1 : c0); d2x += d * d;
        d = v.y - (t2.y ? c1 : c0); d2y += d * d;
    }

    float l0 = 0.f, l1 = 0.f;
    {
        float mx = fmaxf(a0.x, a1.x);
        float e0 = __expf(a0.x - mx), e1 = __expf(a1.x - mx);
        float cf = (t2.x ? e1 : e0) / (e0 + e1);
        float w  = sqrtf(d2x) * cf;
        l0 += t2.x ? 0.f : w; l1 += t2.x ? w : 0.f;
        mx = fmaxf(a0.y, a1.y);
        e0 = __expf(a0.y - mx); e1 = __expf(a1.y - mx);
        cf = (t2.y ? e1 : e0) / (e0 + e1);
        w  = sqrtf(d2y) * cf;
        l0 += t2.y ? 0.f : w; l1 += t2.y ? w : 0.f;
    }

    __shared__ float sm[4][2];
    const int lane = threadIdx.x & 63;
    const int wv   = threadIdx.x >> 6;
    float r0 = waveReduceSum(l0);
    float r1 = waveReduceSum(l1);
    if (lane == 0) { sm[wv][0] = r0; sm[wv][1] = r1; }
    __syncthreads();
    if (threadIdx.x == 0) {
        lossPart[blk * 2 + 0] = sm[0][0] + sm[1][0] + sm[2][0] + sm[3][0];
        lossPart[blk * 2 + 1] = sm[0][1] + sm[1][1] + sm[2][1] + sm[3][1];
    }
}

// Pass 3: final scalar. One block, 256 threads.
__global__ void __launch_bounds__(256) scl_pass3(
    const float* __restrict__ lossPart, const float* __restrict__ counts,
    float* __restrict__ out) {
    float a00 = 0.f, a01 = 0.f, a10 = 0.f, a11 = 0.f;
    for (int blk = threadIdx.x; blk < P2_BLOCKS; blk += 256) {
        const float l0 = lossPart[blk * 2 + 0];
        const float l1 = lossPart[blk * 2 + 1];
        if (blk < P2_PER_B) { a00 += l0; a01 += l1; }
        else                { a10 += l0; a11 += l1; }
    }
    __shared__ float sm[4][4];
    const int lane = threadIdx.x & 63;
    const int wv   = threadIdx.x >> 6;
    float r0 = waveReduceSum(a00);
    float r1 = waveReduceSum(a01);
    float r2 = waveReduceSum(a10);
    float r3 = waveReduceSum(a11);
    if (lane == 0) { sm[wv][0] = r0; sm[wv][1] = r1; sm[wv][2] = r2; sm[wv][3] = r3; }
    __syncthreads();
    if (threadIdx.x == 0) {
        float loss[4];
#pragma unroll
        for (int i = 0; i < 4; ++i)
            loss[i] = sm[0][i] + sm[1][i] + sm[2][i] + sm[3][i];
        float total = 0.f, nv = 0.f;
#pragma unroll
        for (int bk = 0; bk < 4; ++bk) {
            const float cn = counts[bk];
            const float cl = loss[bk] / fmaxf(cn, 1.f);
            if (cn >= 2.f) { total += cl; nv += 1.f; }
        }
        out[0] = (nv > 0.f) ? (total / nv) : 0.f;
    }
}

extern "C" void kernel_launch(void* const* d_in, const int* in_sizes, int n_in,
                              void* d_out, int out_size, void* d_ws, size_t ws_size,
                              hipStream_t stream) {
    const float* feat = (const float*)d_in[0];
    const float* pred = (const float*)d_in[1];
    const int*   tgt  = (const int*)d_in[2];
    float* out = (float*)d_out;

    const int totalVox = in_sizes[2];   // B*N
    const int N = totalVox / BB;        // 393216

    float* ws       = (float*)d_ws;
    float* part     = ws + OFF_PART;
    float* cntPart  = ws + OFF_CNTP;
    float* centers  = ws + OFF_CTR;
    float* counts   = ws + OFF_CNT;
    float* lossPart = ws + OFF_LOSS;

    scl_pass1<<<P1_BLOCKS, 256, 0, stream>>>(feat, tgt, part, cntPart, N);
    scl_reduce<<<1, 64, 0, stream>>>(part, cntPart, centers, counts, N);
    scl_pass2<<<P2_BLOCKS, 256, 0, stream>>>(feat, pred, tgt, centers, lossPart, N);
    scl_pass3<<<1, 256, 0, stream>>>(lossPart, counts, out);
}